// Round 2
// baseline (248.601 us; speedup 1.0000x reference)
//
#include <hip/hip_runtime.h>
#include <hip/hip_bf16.h>
#include <cstdint>
#include <cstddef>

// Problem constants (DeepseekV3Experts: T=1024 H=1024 I=1408 E=8 K=4)
#define NE 8
#define NT 1024
#define NK 4
#define NH 1024
#define NI 1408
#define NA (NT * NK)      // 4096 assignments
#define BM 128            // row tile (bucket granularity)
#define MAXTILES 40
#define MAXPAIRS 24       // sum ceil(tiles_e/2) <= (39+8)/2 = 23
#define PADSLOTS 5120

typedef short short8 __attribute__((ext_vector_type(8)));
typedef float f32x4 __attribute__((ext_vector_type(4)));
typedef float f4v __attribute__((ext_vector_type(4)));
typedef unsigned short u16;

// Workspace layout (bytes).
#define WS_HDR   0
#define WS_SORT  1024
#define WS_XBF   21504      // u16[NT*NH]
#define WS_GT    2118656    // u16[NE*NI*NH]  gate^T [E][I][H]
#define WS_UT    25187328   // u16[NE*NI*NH]  up^T
#define WS_DT    48256000   // u16[NE*NH*NI]  down^T [E][H][I]
#define WS_HB    71324672   // u16[PADSLOTS*NI]

// LDS transpose tile row stride (u16 units). 66 = 33 dwords == 1 (mod 32):
// transposed read rows kc*8+j -> bank offset 8*kc mod 32 in {0,8,16,24} -> 2-way (free).
#define TSTRIDE 66

__device__ __forceinline__ u16 f2b(float f) {
  union { float f; uint32_t u; } c; c.f = f;
  uint32_t u = c.u;
  return (u16)((u + 0x7FFFu + ((u >> 16) & 1u)) >> 16);  // RNE
}

__device__ __forceinline__ void llds16(const void* g, void* l) {
  __builtin_amdgcn_global_load_lds(
      (const __attribute__((address_space(1))) void*)g,
      (__attribute__((address_space(3))) void*)l, 16, 0, 0);
}

// Shared transpose-convert stripe: [K][N] fp32 -> [N][K] bf16, 64k x 128n per block.
__device__ __forceinline__ void transcvt_stripe(const float* __restrict__ src,
                                                u16* __restrict__ dst,
                                                int K, int N, int k0, int n0,
                                                u16* smem, int tid) {
  u16 (*t2)[64][TSTRIDE] = (u16(*)[64][TSTRIDE])smem;
  int r = tid >> 4, c = tid & 15;
  f4v v[2][4];
#pragma unroll
  for (int t = 0; t < 2; ++t)
#pragma unroll
    for (int i = 0; i < 4; ++i)
      v[t][i] = __builtin_nontemporal_load(
          (const f4v*)&src[(size_t)(k0 + r + 16 * i) * N + n0 + t * 64 + c * 4]);
#pragma unroll
  for (int t = 0; t < 2; ++t)
#pragma unroll
    for (int i = 0; i < 4; ++i) {
      ushort4 o;
      o.x = f2b(v[t][i].x); o.y = f2b(v[t][i].y); o.z = f2b(v[t][i].z); o.w = f2b(v[t][i].w);
      *(ushort4*)&t2[t][r + 16 * i][c * 4] = o;
    }
  __syncthreads();
#pragma unroll
  for (int t = 0; t < 2; ++t)
#pragma unroll
    for (int i = 0; i < 2; ++i) {
      int idx = i * 256 + tid;
      int n = idx >> 3, kc = idx & 7;
      u16 o[8];
#pragma unroll
      for (int j = 0; j < 8; ++j) o[j] = t2[t][kc * 8 + j][n];
      *(short8*)&dst[(size_t)(n0 + t * 64 + n) * K + k0 + kc * 8] = *(const short8*)o;
    }
}

// ---------------- K1: all conversions + bucket/pairs + out zero ----------------
// Grid (176, 26): y<16 gate/up stripes; y in 16..23 down stripes; y==24 x convert;
// y==25: x==0 bucket, 1<=x<=64 zero out.
__global__ __launch_bounds__(256) void k1_prep(
    const float* __restrict__ gw, const float* __restrict__ uw, const float* __restrict__ dw,
    const float* __restrict__ hs, const int* __restrict__ sel,
    u16* __restrict__ gT, u16* __restrict__ uT, u16* __restrict__ dT, u16* __restrict__ xbf,
    int* __restrict__ hdr, int* __restrict__ sorted, float* __restrict__ outz) {
  int tid = threadIdx.x;
  int y = blockIdx.y;
  if (y == 24) {  // hidden_states convert
    for (int i = blockIdx.x * 256 + tid; i * 4 < NT * NH; i += 176 * 256) {
      f4v v = __builtin_nontemporal_load((const f4v*)&hs[i * 4]);
      ushort4 o;
      o.x = f2b(v.x); o.y = f2b(v.y); o.z = f2b(v.z); o.w = f2b(v.w);
      *(ushort4*)&xbf[i * 4] = o;
    }
    return;
  }
  if (y == 25) {
    int x = blockIdx.x;
    if (x >= 1 && x <= 64) {  // zero out
      int base = (x - 1) * 16384;
      f4v z = {0.f, 0.f, 0.f, 0.f};
#pragma unroll
      for (int i = 0; i < 16; ++i)
        *(f4v*)&outz[base + (i * 256 + tid) * 4] = z;
      return;
    }
    if (x != 0) return;
    __shared__ int cnt[NE], fill[NE], poff_s[NE + 1];
    if (tid < NE) { cnt[tid] = 0; fill[tid] = 0; }
    __syncthreads();
    for (int i = tid; i < NA; i += 256) atomicAdd(&cnt[sel[i]], 1);
    __syncthreads();
    if (tid == 0) {
      int off = 0, nt = 0, np = 0;
      for (int e = 0; e < NE; ++e) {
        poff_s[e] = off;
        int tiles = (cnt[e] + BM - 1) / BM;
        for (int j = 0; j < tiles; ++j) { hdr[32 + nt] = e; hdr[80 + nt] = off + j * BM; ++nt; }
        // pair consecutive tiles of the same expert (shared B panel in k2/k3)
        for (int j = 0; j < tiles; j += 2) {
          hdr[128 + np] = e;
          hdr[160 + np] = off + j * BM;
          hdr[192 + np] = (j + 1 < tiles) ? (off + (j + 1) * BM) : -1;
          ++np;
        }
        off += tiles * BM;
      }
      poff_s[NE] = off;
      hdr[17] = nt; hdr[18] = np;
      for (int e = 0; e < NE; ++e) hdr[e] = cnt[e];
      for (int e = 0; e <= NE; ++e) hdr[8 + e] = poff_s[e];
    }
    __syncthreads();
    for (int i = tid; i < PADSLOTS; i += 256) sorted[i] = -1;
    __syncthreads();
    for (int i = tid; i < NA; i += 256) {
      int e = sel[i];
      int p = atomicAdd(&fill[e], 1);
      sorted[poff_s[e] + p] = i;
    }
    return;
  }
  __shared__ u16 smem[2 * 64 * TSTRIDE];
  if (y < 16) {   // gate/up: K=NH, N=NI
    int tensor = y >> 3, e = y & 7;
    const float* src = ((tensor == 0) ? gw : uw) + (size_t)e * NH * NI;
    u16* dst = ((tensor == 0) ? gT : uT) + (size_t)e * NH * NI;
    int nb = blockIdx.x % 11, kb = blockIdx.x / 11;
    transcvt_stripe(src, dst, NH, NI, kb * 64, nb * 128, smem, tid);
  } else {        // down: K=NI, N=NH
    int e = y - 16;
    const float* src = dw + (size_t)e * NI * NH;
    u16* dst = dT + (size_t)e * NI * NH;
    int nb = blockIdx.x % 8, kb = blockIdx.x / 8;
    transcvt_stripe(src, dst, NI, NH, kb * 64, nb * 128, smem, tid);
  }
}

// ---------------- K2: gemm1, 256x128 paired tile, 1024 thr, dbuf prefetch ----------------
// Grid MAXPAIRS*11: p = b/11, n0 = (b%11)*128. 16 waves as 4m x 4n; wave tile 64m x 32n
// per tensor; acc = 16 frags = 64 VGPR (fits 16 waves/CU at <=128 regs).
// LDS 128 KB: 2 bufs x (A[256x64] | Bg[128x64] | Bu[128x64]).
// Staged traffic: B halves vs 128-tile (two row-tiles share one B stage) -> 345->227 MB.
__global__ __launch_bounds__(1024, 4) void k2_gemm1(
    const u16* __restrict__ xbf, const u16* __restrict__ gT, const u16* __restrict__ uT,
    u16* __restrict__ hbuf, const int* __restrict__ hdr, const int* __restrict__ sorted) {
  __shared__ u16 smem[65536];   // 128 KB
  int b = blockIdx.x;
  int p = b / 11, n0 = (b % 11) * 128;
  if (p >= hdr[18]) return;
  int e = hdr[128 + p], slotA = hdr[160 + p], slotB = hdr[192 + p];
  int tid = threadIdx.x;

  // A staging sources: 256 rows (two 128-row tiles), 2 chunks/thread
  const u16* aptr[2];
#pragma unroll
  for (int s = 0; s < 2; ++s) {
    int idx = s * 1024 + tid;
    int row = idx >> 3, c = idx & 7;
    int kc = c ^ (row & 7);
    int srow = (row < 128) ? (slotA + row) : (slotB >= 0 ? slotB + row - 128 : 0);
    int as = sorted[srow];
    int trow = (as >= 0) ? (as >> 2) : 0;
    aptr[s] = xbf + (size_t)trow * NH + kc * 8;
  }
  // B staging sources: 128 cols, 1 chunk/thread each tensor
  {
  }
  int bn = tid >> 3, bc = tid & 7;
  int bkc = bc ^ (bn & 7);
  size_t bo = ((size_t)e * NI + n0 + bn) * NH + bkc * 8;
  const u16* bgp = gT + bo;
  const u16* bup = uT + bo;

  int lane = tid & 63, wave = tid >> 6;
  int wm = wave >> 2, wn = wave & 3;
  int l15 = lane & 15, quad = lane >> 4;
  int sw = l15 & 7;

  f32x4 accg[4][2] = {}; f32x4 accu[4][2] = {};

  // buf layout (u16 units): buf*32768 + {A:0, Bg:16384, Bu:24576}
#define K2_STAGE(BUF, KT)                                                     \
  {                                                                           \
    int ko_ = (KT) * 64;                                                      \
    u16* base_ = smem + (BUF) * 32768;                                        \
    llds16(aptr[0] + ko_, base_ + tid * 8);                                   \
    llds16(aptr[1] + ko_, base_ + (1024 + tid) * 8);                          \
    llds16(bgp + ko_, base_ + 16384 + tid * 8);                               \
    llds16(bup + ko_, base_ + 24576 + tid * 8);                               \
  }

  K2_STAGE(0, 0);
  __syncthreads();
  for (int kt = 0; kt < 16; ++kt) {
    int cur = kt & 1;
    if (kt < 15) K2_STAGE(cur ^ 1, kt + 1);
    const u16* sA  = smem + cur * 32768;
    const u16* sBg = sA + 16384;
    const u16* sBu = sA + 24576;
#pragma unroll
    for (int ks = 0; ks < 2; ++ks) {
      int pos = ((ks * 4 + quad) ^ sw) * 8;
      short8 av[4], bg[2], bu[2];
#pragma unroll
      for (int mf = 0; mf < 4; ++mf)
        av[mf] = *(const short8*)&sA[(wm * 64 + mf * 16 + l15) * 64 + pos];
#pragma unroll
      for (int nf = 0; nf < 2; ++nf) {
        bg[nf] = *(const short8*)&sBg[(wn * 32 + nf * 16 + l15) * 64 + pos];
        bu[nf] = *(const short8*)&sBu[(wn * 32 + nf * 16 + l15) * 64 + pos];
      }
#pragma unroll
      for (int mf = 0; mf < 4; ++mf)
#pragma unroll
        for (int nf = 0; nf < 2; ++nf) {
          accg[mf][nf] = __builtin_amdgcn_mfma_f32_16x16x32_bf16(av[mf], bg[nf], accg[mf][nf], 0, 0, 0);
          accu[mf][nf] = __builtin_amdgcn_mfma_f32_16x16x32_bf16(av[mf], bu[nf], accu[mf][nf], 0, 0, 0);
        }
    }
    __syncthreads();   // drains this iter's prefetch (vmcnt 0) + protects cur for overwrite
  }

#pragma unroll
  for (int mf = 0; mf < 4; ++mf)
#pragma unroll
    for (int r = 0; r < 4; ++r) {
      int row = wm * 64 + mf * 16 + quad * 4 + r;
      int slot = (row < 128) ? (slotA + row) : (slotB >= 0 ? slotB + row - 128 : -1);
      if (slot < 0) continue;
#pragma unroll
      for (int nf = 0; nf < 2; ++nf) {
        int col = n0 + wn * 32 + nf * 16 + l15;
        float g2 = accg[mf][nf][r], u = accu[mf][nf][r];
        float hv = (g2 / (1.f + __expf(-g2))) * u;
        hbuf[(size_t)slot * NI + col] = f2b(hv);
      }
    }
#undef K2_STAGE
}

// ---------------- K3: down proj, 256x128 paired tile, K split in 2, atomic combine ----------
// Grid MAXPAIRS*16: p = b>>4; n0 = ((b&15)&7)*128; kh = (b&15)>>3.
// 16 waves 4m x 4n, wave 64m x 32n, acc 32 VGPR. LDS 96 KB dbuf.
// Staged: B halves via pairing -> 230->173 MB; K-split keeps 384 blocks (CU-filling).
__global__ __launch_bounds__(1024, 4) void k3_gemm2(
    const u16* __restrict__ hbuf, const u16* __restrict__ dT,
    const float* __restrict__ rw, float* __restrict__ out,
    const int* __restrict__ hdr, const int* __restrict__ sorted) {
  __shared__ u16 smem[49152];   // 96 KB: 2 bufs x (A 16384 | B 8192)
  int b = blockIdx.x;
  int p = b >> 4, r16 = b & 15;
  int n0 = (r16 & 7) * 128, kh = r16 >> 3;
  if (p >= hdr[18]) return;
  int e = hdr[128 + p], slotA = hdr[160 + p], slotB = hdr[192 + p];
  int tid = threadIdx.x;

  const u16* aptr[2];
#pragma unroll
  for (int s = 0; s < 2; ++s) {
    int idx = s * 1024 + tid;
    int row = idx >> 3, c = idx & 7;
    int kc = c ^ (row & 7);
    int slot = (row < 128) ? (slotA + row) : (slotB >= 0 ? slotB + row - 128 : 0);
    aptr[s] = hbuf + (size_t)slot * NI + kc * 8;
  }
  int bn = tid >> 3, bc = tid & 7;
  int bkc = bc ^ (bn & 7);
  const u16* bp = dT + ((size_t)e * NH + n0 + bn) * NI + bkc * 8;

  int lane = tid & 63, wave = tid >> 6;
  int wm = wave >> 2, wn = wave & 3;
  int l15 = lane & 15, quad = lane >> 4;
  int sw = l15 & 7;

  f32x4 acc[4][2] = {};

#define K3_STAGE(BUF, KT)                                                     \
  {                                                                           \
    int ko_ = (KT) * 64;                                                      \
    u16* base_ = smem + (BUF) * 24576;                                        \
    llds16(aptr[0] + ko_, base_ + tid * 8);                                   \
    llds16(aptr[1] + ko_, base_ + (1024 + tid) * 8);                          \
    llds16(bp + ko_, base_ + 16384 + tid * 8);                                \
  }

  int kt0 = kh * 11;
  K3_STAGE(0, kt0);
  __syncthreads();
  for (int ki = 0; ki < 11; ++ki) {
    int cur = ki & 1;
    if (ki < 10) K3_STAGE(cur ^ 1, kt0 + ki + 1);
    const u16* sA = smem + cur * 24576;
    const u16* sB = sA + 16384;
#pragma unroll
    for (int ks = 0; ks < 2; ++ks) {
      int pos = ((ks * 4 + quad) ^ sw) * 8;
      short8 av[4], bv[2];
#pragma unroll
      for (int mf = 0; mf < 4; ++mf)
        av[mf] = *(const short8*)&sA[(wm * 64 + mf * 16 + l15) * 64 + pos];
#pragma unroll
      for (int nf = 0; nf < 2; ++nf)
        bv[nf] = *(const short8*)&sB[(wn * 32 + nf * 16 + l15) * 64 + pos];
#pragma unroll
      for (int mf = 0; mf < 4; ++mf)
#pragma unroll
        for (int nf = 0; nf < 2; ++nf)
          acc[mf][nf] = __builtin_amdgcn_mfma_f32_16x16x32_bf16(av[mf], bv[nf], acc[mf][nf], 0, 0, 0);
    }
    __syncthreads();
  }

  // weighted combine: out[token] += rw[assignment] * partial_down_row
#pragma unroll
  for (int mf = 0; mf < 4; ++mf)
#pragma unroll
    for (int r = 0; r < 4; ++r) {
      int row = wm * 64 + mf * 16 + quad * 4 + r;
      int slot = (row < 128) ? (slotA + row) : (slotB >= 0 ? slotB + row - 128 : -1);
      if (slot < 0) continue;
      int as = sorted[slot];
      if (as < 0) continue;
      float w = rw[as];
      float* orow = out + (size_t)(as >> 2) * NH + n0 + wn * 32;
#pragma unroll
      for (int nf = 0; nf < 2; ++nf)
        atomicAdd(&orow[nf * 16 + l15], w * acc[mf][nf][r]);
    }
#undef K3_STAGE
}

extern "C" void kernel_launch(void* const* d_in, const int* in_sizes, int n_in,
                              void* d_out, int out_size, void* d_ws, size_t ws_size,
                              hipStream_t stream) {
  const float* hs  = (const float*)d_in[0];
  const float* rw  = (const float*)d_in[1];
  const float* gw  = (const float*)d_in[2];
  const float* uw  = (const float*)d_in[3];
  const float* dw  = (const float*)d_in[4];
  const int*   sel = (const int*)d_in[5];
  float* out = (float*)d_out;

  char* ws = (char*)d_ws;
  int*  hdr    = (int*)(ws + WS_HDR);
  int*  sorted = (int*)(ws + WS_SORT);
  u16*  xbf    = (u16*)(ws + WS_XBF);
  u16*  gT     = (u16*)(ws + WS_GT);
  u16*  uT     = (u16*)(ws + WS_UT);
  u16*  dT     = (u16*)(ws + WS_DT);
  u16*  hb     = (u16*)(ws + WS_HB);

  hipLaunchKernelGGL(k1_prep, dim3(176, 26), dim3(256), 0, stream,
                     gw, uw, dw, hs, sel, gT, uT, dT, xbf, hdr, sorted, out);
  hipLaunchKernelGGL(k2_gemm1, dim3(MAXPAIRS * 11), dim3(1024), 0, stream,
                     xbf, gT, uT, hb, hdr, sorted);
  hipLaunchKernelGGL(k3_gemm2, dim3(MAXPAIRS * 16), dim3(1024), 0, stream,
                     hb, dT, rw, out, hdr, sorted);
}